// Round 1
// baseline (404.057 us; speedup 1.0000x reference)
//
#include <hip/hip_runtime.h>
#include <stdint.h>

typedef unsigned short u16;
typedef __attribute__((ext_vector_type(4))) float f32x4;
typedef __attribute__((ext_vector_type(4))) unsigned short u16x4;
typedef __attribute__((ext_vector_type(8))) unsigned short u16x8;
typedef __attribute__((ext_vector_type(8))) short s16x8;
typedef __attribute__((ext_vector_type(4))) unsigned int u32x4;

#define DEVI static __device__ __forceinline__

// f32 -> bf16 round-to-nearest-even
DEVI u16 f2b(float f) {
  union { float f; unsigned u; } v; v.f = f;
  unsigned r = v.u + 0x7fffu + ((v.u >> 16) & 1u);
  return (u16)(r >> 16);
}

// async global->LDS, 16B per lane. LDS dest must be wave-uniform base + lane*16.
DEVI void gload_lds16(const void* gptr, void* lptr) {
  typedef const __attribute__((address_space(1))) unsigned gq;
  typedef __attribute__((address_space(3))) unsigned lq;
  __builtin_amdgcn_global_load_lds((gq*)(uintptr_t)gptr,
                                   (lq*)(uint32_t)(uintptr_t)lptr, 16, 0, 0);
}

// ---------------------------------------------------------------------------
// f32 -> bf16 conversion (vectorized, grid-stride)
// ---------------------------------------------------------------------------
__global__ __launch_bounds__(256) void cvt_bf16(const float* __restrict__ src,
                                                u16* __restrict__ dst, int n4) {
  int i = blockIdx.x * 256 + threadIdx.x;
  const int stride = gridDim.x * 256;
  for (; i < n4; i += stride) {
    f32x4 v = *(const f32x4*)(src + (size_t)i * 4);
    u16x4 o;
    o[0] = f2b(v[0]); o[1] = f2b(v[1]); o[2] = f2b(v[2]); o[3] = f2b(v[3]);
    *(u16x4*)(dst + (size_t)i * 4) = o;
  }
}

// ---------------------------------------------------------------------------
// GEMM: C[M,N] (f32) = A[M,K] (bf16, row-major) * B[N,K]^T (bf16, row-major)
// 128x128 tile, BK=64, 4 waves (2x2), 16x16x32 bf16 MFMA  (m97 structure)
// Requires M%128==0, N%128==0, K%64==0.
// ---------------------------------------------------------------------------
__global__ __launch_bounds__(256) void gemm_bt(const u16* __restrict__ A,
                                               const u16* __restrict__ B,
                                               float* __restrict__ C,
                                               int M, int N, int K) {
  __shared__ __align__(16) u16 As[128 * 64];
  __shared__ __align__(16) u16 Bs[128 * 64];
  const int tid = threadIdx.x;
  const int lane = tid & 63, w = tid >> 6;
  const int wm = w >> 1, wn = w & 1;
  const int c15 = lane & 15, g = lane >> 4;
  const int m0 = blockIdx.y * 128, n0 = blockIdx.x * 128;
  f32x4 acc[4][4] = {};

  for (int k0 = 0; k0 < K; k0 += 64) {
#pragma unroll
    for (int p = 0; p < 4; ++p) {
      const int c = tid + p * 256;            // 1024 chunks of 16B
      const int row = c >> 3, ko = (c & 7) * 8;
      gload_lds16(A + (size_t)(m0 + row) * K + k0 + ko, &As[c * 8]);
    }
#pragma unroll
    for (int p = 0; p < 4; ++p) {
      const int c = tid + p * 256;
      const int row = c >> 3, ko = (c & 7) * 8;
      gload_lds16(B + (size_t)(n0 + row) * K + k0 + ko, &Bs[c * 8]);
    }
    __syncthreads();
#pragma unroll
    for (int kk = 0; kk < 64; kk += 32) {
      s16x8 af[4], bfr[4];
#pragma unroll
      for (int i = 0; i < 4; ++i)
        af[i] = *(const s16x8*)&As[(wm * 64 + i * 16 + c15) * 64 + kk + g * 8];
#pragma unroll
      for (int i = 0; i < 4; ++i)
        bfr[i] = *(const s16x8*)&Bs[(wn * 64 + i * 16 + c15) * 64 + kk + g * 8];
#pragma unroll
      for (int i = 0; i < 4; ++i)
#pragma unroll
        for (int j = 0; j < 4; ++j)
          acc[i][j] = __builtin_amdgcn_mfma_f32_16x16x32_bf16(af[i], bfr[j], acc[i][j], 0, 0, 0);
    }
    __syncthreads();
  }
  // C/D layout: col = lane&15, row = (lane>>4)*4 + reg
#pragma unroll
  for (int i = 0; i < 4; ++i)
#pragma unroll
    for (int j = 0; j < 4; ++j) {
      const int mr = m0 + wm * 64 + i * 16 + g * 4;
      const int nc = n0 + wn * 64 + j * 16 + c15;
#pragma unroll
      for (int r = 0; r < 4; ++r)
        C[(size_t)(mr + r) * N + nc] = acc[i][j][r];
    }
}

// ---------------------------------------------------------------------------
// Per-row: RMSNorm(q_a[0:1024]) -> qn bf16 ; RMSNorm(ckv[0:896]) -> kvn bf16 ;
// RoPE(ckv[896:960]) -> kr bf16.  C1 row layout: [q_a(1024) | ckv(960) | pad]
// ---------------------------------------------------------------------------
DEVI float block_sum(float v, float* sbuf, int tid) {
#pragma unroll
  for (int o = 32; o; o >>= 1) v += __shfl_xor(v, o, 64);
  __syncthreads();
  if ((tid & 63) == 0) sbuf[tid >> 6] = v;
  __syncthreads();
  return sbuf[0] + sbuf[1] + sbuf[2] + sbuf[3];
}

__global__ __launch_bounds__(256) void norm_rope(const float* __restrict__ C1,
    const float* __restrict__ qw, const float* __restrict__ kw,
    const float* __restrict__ cosb, const float* __restrict__ sinb,
    u16* __restrict__ qn, u16* __restrict__ kvn, u16* __restrict__ kr) {
  __shared__ float sbuf[4];
  const int s = blockIdx.x, tid = threadIdx.x;
  const float* row = C1 + (size_t)s * 2048;

  // q part (1024)
  f32x4 qv = *(const f32x4*)(row + tid * 4);
  float ss = qv[0]*qv[0] + qv[1]*qv[1] + qv[2]*qv[2] + qv[3]*qv[3];
  ss = block_sum(ss, sbuf, tid);
  const float scale = rsqrtf(ss * (1.f / 1024.f) + 1e-6f);
  {
    f32x4 wv = *(const f32x4*)(qw + tid * 4);
    u16x4 o;
#pragma unroll
    for (int j = 0; j < 4; ++j) o[j] = f2b(qv[j] * scale * wv[j]);
    *(u16x4*)(qn + (size_t)s * 1024 + tid * 4) = o;
  }

  // kv part (896)
  float ss2 = 0.f;
  f32x4 kvv = {};
  if (tid < 224) {
    kvv = *(const f32x4*)(row + 1024 + tid * 4);
    ss2 = kvv[0]*kvv[0] + kvv[1]*kvv[1] + kvv[2]*kvv[2] + kvv[3]*kvv[3];
  }
  ss2 = block_sum(ss2, sbuf, tid);
  const float sc2 = rsqrtf(ss2 * (1.f / 896.f) + 1e-6f);
  if (tid < 224) {
    f32x4 wv = *(const f32x4*)(kw + tid * 4);
    u16x4 o;
#pragma unroll
    for (int j = 0; j < 4; ++j) o[j] = f2b(kvv[j] * sc2 * wv[j]);
    *(u16x4*)(kvn + (size_t)s * 896 + tid * 4) = o;
  }

  // k_rope (64)
  if (tid < 64) {
    const int d = tid;
    const float x = row[1920 + d];
    const float part = row[1920 + (d < 32 ? d + 32 : d - 32)];
    const float cv = cosb[s * 64 + d], sv = sinb[s * 64 + d];
    kr[(size_t)s * 64 + d] = f2b(d < 32 ? (x * cv - part * sv) : (x * cv + part * sv));
  }
}

// ---------------------------------------------------------------------------
// Vt[h][d][s] = bf16(kvraw[s][h*128 + 64 + d])   (LDS-tiled transpose)
// ---------------------------------------------------------------------------
__global__ __launch_bounds__(256) void vt_epi(const float* __restrict__ kvraw,
                                              u16* __restrict__ Vt) {
  __shared__ u16 t[64 * 66];
  const int s0 = blockIdx.x * 64, h = blockIdx.y, tid = threadIdx.x;
#pragma unroll
  for (int j = 0; j < 16; ++j) {
    const int idx = tid + j * 256;
    const int d = idx & 63, r = idx >> 6;
    t[r * 66 + d] = f2b(kvraw[(size_t)(s0 + r) * 4096 + h * 128 + 64 + d]);
  }
  __syncthreads();
#pragma unroll
  for (int j = 0; j < 4; ++j) {
    const int idx = tid + j * 256;       // 1024 chunks: 4 consecutive s each
    const int r4 = (idx & 15) * 4, d = idx >> 4;
    u16x4 o;
#pragma unroll
    for (int r = 0; r < 4; ++r) o[r] = t[(r4 + r) * 66 + d];
    *(u16x4*)(Vt + ((size_t)h * 64 + d) * 2048 + s0 + r4) = o;
  }
}

// ---------------------------------------------------------------------------
// Causal flash attention. Block = (q-tile of 64 rows, head). 4 waves x 16 rows.
// scores^T = mfma(K, Q^T); O^T = mfma(V^T, P^T). Q built in-reg with RoPE.
// ---------------------------------------------------------------------------
__global__ __launch_bounds__(256) void attn_fwd(
    const float* __restrict__ qraw, const float* __restrict__ kvraw,
    const u16* __restrict__ kr, const u16* __restrict__ Vt,
    const float* __restrict__ cosb, const float* __restrict__ sinb,
    u16* __restrict__ attn) {
  __shared__ __align__(16) u16 Klds[32 * 128];  // [kv][128] bf16
  __shared__ __align__(16) u16 Vlds[64 * 32];   // [d][kv]   bf16
  const int tid = threadIdx.x;
  const int lane = tid & 63, w = tid >> 6;
  const int qb = blockIdx.x, h = blockIdx.y;
  const int c15 = lane & 15, g = lane >> 4;
  const int qrow = qb * 64 + w * 16 + c15;

  // Q fragments (B operand): elem i -> Q[qrow][d0*32 + g*8 + i], RoPE on d>=64
  s16x8 qf[4];
  {
    const float* qp = qraw + (size_t)qrow * 4096 + h * 128;
    float f[4][8];
#pragma unroll
    for (int d0 = 0; d0 < 4; ++d0) {
      f32x4 a = *(const f32x4*)(qp + d0 * 32 + g * 8);
      f32x4 b = *(const f32x4*)(qp + d0 * 32 + g * 8 + 4);
#pragma unroll
      for (int i = 0; i < 4; ++i) { f[d0][i] = a[i]; f[d0][4 + i] = b[i]; }
    }
    const float* cb = cosb + (size_t)qrow * 64;
    const float* sb = sinb + (size_t)qrow * 64;
    float cj[8], sj[8], c2[8], s2[8];
    {
      f32x4 a0 = *(const f32x4*)(cb + g * 8), a1 = *(const f32x4*)(cb + g * 8 + 4);
      f32x4 b0 = *(const f32x4*)(sb + g * 8), b1 = *(const f32x4*)(sb + g * 8 + 4);
      f32x4 e0 = *(const f32x4*)(cb + 32 + g * 8), e1 = *(const f32x4*)(cb + 32 + g * 8 + 4);
      f32x4 d0v = *(const f32x4*)(sb + 32 + g * 8), d1v = *(const f32x4*)(sb + 32 + g * 8 + 4);
#pragma unroll
      for (int i = 0; i < 4; ++i) {
        cj[i] = a0[i]; cj[4 + i] = a1[i];
        sj[i] = b0[i]; sj[4 + i] = b1[i];
        c2[i] = e0[i]; c2[4 + i] = e1[i];
        s2[i] = d0v[i]; s2[4 + i] = d1v[i];
      }
    }
#pragma unroll
    for (int i = 0; i < 8; ++i) {
      qf[0][i] = (short)f2b(f[0][i]);
      qf[1][i] = (short)f2b(f[1][i]);
      qf[2][i] = (short)f2b(f[2][i] * cj[i] - f[3][i] * sj[i]);
      qf[3][i] = (short)f2b(f[3][i] * c2[i] + f[2][i] * s2[i]);
    }
  }

  f32x4 acc[4] = {};
  float m = -1e9f, ssum = 0.f;
  const int srcA = (((2 * g) & 3) << 4) | c15;
  const int srcB = (((2 * g + 1) & 3) << 4) | c15;
  const bool sel = (g >> 1) != 0;
  const int nt = (qb + 1) * 2;

  for (int t = 0; t < nt; ++t) {
    const int kv0 = t * 32;
    {
      // K tile: cols 0..63 from kvraw (f32 -> bf16), cols 64..127 from kr
      const int row = tid >> 3, sg = tid & 7;
      const float* src = kvraw + (size_t)(kv0 + row) * 4096 + h * 128 + sg * 8;
      f32x4 x0 = *(const f32x4*)src;
      f32x4 x1 = *(const f32x4*)(src + 4);
      s16x8 nv;
#pragma unroll
      for (int i = 0; i < 4; ++i) { nv[i] = (short)f2b(x0[i]); nv[4 + i] = (short)f2b(x1[i]); }
      *(s16x8*)&Klds[row * 128 + sg * 8] = nv;
      *(s16x8*)&Klds[row * 128 + 64 + sg * 8] =
          *(const s16x8*)(kr + (size_t)(kv0 + row) * 64 + sg * 8);
      // V^T tile via async direct-to-LDS
      const int d = tid >> 2, ko = (tid & 3) * 8;
      gload_lds16(Vt + ((size_t)h * 64 + d) * 2048 + kv0 + ko, &Vlds[tid * 8]);
    }
    __syncthreads();

    // scores^T: row = kv (g*4+r per 16-half), col = q (c15)
    f32x4 sT[2];
#pragma unroll
    for (int kvh = 0; kvh < 2; ++kvh) {
      f32x4 s4 = {};
#pragma unroll
      for (int d0 = 0; d0 < 4; ++d0) {
        s16x8 kf = *(const s16x8*)&Klds[(kvh * 16 + c15) * 128 + d0 * 32 + g * 8];
        s4 = __builtin_amdgcn_mfma_f32_16x16x32_bf16(kf, qf[d0], s4, 0, 0, 0);
      }
      sT[kvh] = s4;
    }

    float pv[2][4];
    float pm = -1e9f;
#pragma unroll
    for (int kvh = 0; kvh < 2; ++kvh)
#pragma unroll
      for (int r = 0; r < 4; ++r) {
        const int kv = kv0 + kvh * 16 + g * 4 + r;
        float sc = sT[kvh][r] * 0.08838834764831845f;  // (HD+MD)^-0.5
        sc = (kv <= qrow) ? sc : -1e9f;
        pv[kvh][r] = sc;
        pm = fmaxf(pm, sc);
      }
    pm = fmaxf(pm, __shfl_xor(pm, 16, 64));
    pm = fmaxf(pm, __shfl_xor(pm, 32, 64));
    const float mnew = fmaxf(m, pm);
    const float alpha = __expf(m - mnew);
    float rs = 0.f;
#pragma unroll
    for (int kvh = 0; kvh < 2; ++kvh)
#pragma unroll
      for (int r = 0; r < 4; ++r) {
        const float p = __expf(pv[kvh][r] - mnew);
        pv[kvh][r] = p;
        rs += p;
      }
    rs += __shfl_xor(rs, 16, 64);
    rs += __shfl_xor(rs, 32, 64);
    ssum = ssum * alpha + rs;
    m = mnew;
#pragma unroll
    for (int dt = 0; dt < 4; ++dt) acc[dt] *= alpha;

    // rearrange P^T (4-consecutive-k per lane-group) into x32 B layout (8-consecutive)
    unsigned pw00 = (unsigned)f2b(pv[0][0]) | ((unsigned)f2b(pv[0][1]) << 16);
    unsigned pw01 = (unsigned)f2b(pv[0][2]) | ((unsigned)f2b(pv[0][3]) << 16);
    unsigned pw10 = (unsigned)f2b(pv[1][0]) | ((unsigned)f2b(pv[1][1]) << 16);
    unsigned pw11 = (unsigned)f2b(pv[1][2]) | ((unsigned)f2b(pv[1][3]) << 16);
    unsigned a00 = (unsigned)__shfl((int)pw00, srcA, 64);
    unsigned a01 = (unsigned)__shfl((int)pw01, srcA, 64);
    unsigned a10 = (unsigned)__shfl((int)pw10, srcA, 64);
    unsigned a11 = (unsigned)__shfl((int)pw11, srcA, 64);
    unsigned b00 = (unsigned)__shfl((int)pw00, srcB, 64);
    unsigned b01 = (unsigned)__shfl((int)pw01, srcB, 64);
    unsigned b10 = (unsigned)__shfl((int)pw10, srcB, 64);
    unsigned b11 = (unsigned)__shfl((int)pw11, srcB, 64);
    u32x4 bw;
    bw[0] = sel ? a10 : a00;
    bw[1] = sel ? a11 : a01;
    bw[2] = sel ? b10 : b00;
    bw[3] = sel ? b11 : b01;
    const s16x8 pB = __builtin_bit_cast(s16x8, bw);
#pragma unroll
    for (int dt = 0; dt < 4; ++dt) {
      s16x8 vf = *(const s16x8*)&Vlds[(dt * 16 + c15) * 32 + g * 8];
      acc[dt] = __builtin_amdgcn_mfma_f32_16x16x32_bf16(vf, pB, acc[dt], 0, 0, 0);
    }
    __syncthreads();
  }

  const float inv = 1.f / ssum;
#pragma unroll
  for (int dt = 0; dt < 4; ++dt) {
    u16x4 o;
#pragma unroll
    for (int r = 0; r < 4; ++r) o[r] = f2b(acc[dt][r] * inv);
    *(u16x4*)(attn + (size_t)qrow * 2048 + h * 64 + dt * 16 + g * 4) = o;
  }
}

// ---------------------------------------------------------------------------
extern "C" void kernel_launch(void* const* d_in, const int* in_sizes, int n_in,
                              void* d_out, int out_size, void* d_ws, size_t ws_size,
                              hipStream_t stream) {
  const float* X    = (const float*)d_in[0];
  const float* cosb = (const float*)d_in[1];
  const float* sinb = (const float*)d_in[2];
  const float* Wqa  = (const float*)d_in[3];
  const float* qlnw = (const float*)d_in[4];
  const float* Wqb  = (const float*)d_in[5];
  const float* Wkva = (const float*)d_in[6];
  const float* klnw = (const float*)d_in[7];
  const float* Wkvb = (const float*)d_in[8];
  const float* Wo   = (const float*)d_in[9];
  float* out = (float*)d_out;
  char* ws = (char*)d_ws;

  // workspace layout (bytes); total 107,741,184 (~102.8 MiB)
  u16*   Xb    = (u16*)(ws + 0);          //  8 MiB  (dies after GEMM1)
  u16*   W1    = (u16*)(ws + 8388608);    //  8 MiB  [Wqa rows 0..1023 | Wkva 1024..1983 | pad]
  float* C1    = (float*)(ws + 16777216); // 16 MiB  (dies after norm)
  u16*   qn    = (u16*)(ws + 33554432);   //  4 MiB
  u16*   kvn   = (u16*)(ws + 37748736);   //  3.5 MiB
  u16*   kr    = (u16*)(ws + 41418752);   //  0.25 MiB
  u16*   Wqbb  = (u16*)(ws + 41680896);   //  8 MiB  (Wo overlays after GEMM2a)
  u16*   Wkvbb = (u16*)(ws + 50069504);   //  7 MiB
  float* qraw  = (float*)(ws + 0);        // 32 MiB, overlays Xb|W1|C1
  float* kvraw = (float*)(ws + 57409536); // 32 MiB
  u16*   VtG   = (u16*)(ws + 90963968);   //  8 MiB
  u16*   attnb = (u16*)(ws + 99352576);   //  8 MiB
  u16*   Wob   = Wqbb;

  auto cvt = [&](const float* s, u16* d, int n4) {
    int blocks = (n4 + 255) / 256; if (blocks > 1024) blocks = 1024;
    cvt_bf16<<<blocks, 256, 0, stream>>>(s, d, n4);
  };
  auto gemm = [&](const u16* A, const u16* B, float* C, int M, int N, int K) {
    dim3 grid(N / 128, M / 128);
    gemm_bt<<<grid, 256, 0, stream>>>(A, B, C, M, N, K);
  };

  // 1. convert inputs/weights to bf16
  cvt(X,    Xb,                 2048 * 2048 / 4);
  cvt(Wqa,  W1,                 1024 * 2048 / 4);
  cvt(Wkva, W1 + 1024 * 2048,    960 * 2048 / 4);
  cvt(Wqb,  Wqbb,               4096 * 1024 / 4);
  cvt(Wkvb, Wkvbb,              4096 * 896 / 4);

  // 2. C1 = X @ [Wqa;Wkva]^T  (cols: 0..1023 q_a, 1024..1983 ckv, rest pad)
  gemm(Xb, W1, C1, 2048, 2048, 2048);

  // 3. RMSNorm + k_rope RoPE
  norm_rope<<<2048, 256, 0, stream>>>(C1, qlnw, klnw, cosb, sinb, qn, kvn, kr);

  // 4. qraw = qn @ Wqb^T ; kvraw = kvn @ Wkvb^T   (f32 outputs)
  gemm(qn, Wqbb, qraw, 2048, 4096, 1024);
  gemm(kvn, Wkvbb, kvraw, 2048, 4096, 896);

  // 5. Wo -> bf16 (overlays Wqbb, dead after GEMM2a)
  cvt(Wo, Wob, 2048 * 2048 / 4);

  // 6. V^T layout
  vt_epi<<<dim3(32, 32), 256, 0, stream>>>(kvraw, VtG);

  // 7. causal attention
  attn_fwd<<<dim3(32, 32), 256, 0, stream>>>(qraw, kvraw, kr, VtG, cosb, sinb, attnb);

  // 8. out = attn @ Wo^T
  gemm(attnb, Wob, out, 2048, 2048, 2048);
}

// Round 2
// 270.194 us; speedup vs baseline: 1.4954x; 1.4954x over previous
//
#include <hip/hip_runtime.h>
#include <stdint.h>

typedef unsigned short u16;
typedef __attribute__((ext_vector_type(4))) float f32x4;
typedef __attribute__((ext_vector_type(4))) unsigned short u16x4;
typedef __attribute__((ext_vector_type(8))) unsigned short u16x8;
typedef __attribute__((ext_vector_type(8))) short s16x8;
typedef __attribute__((ext_vector_type(4))) short s16x4;
typedef __attribute__((ext_vector_type(2))) unsigned int u32x2;

#define DEVI static __device__ __forceinline__

// f32 -> bf16 round-to-nearest-even
DEVI u16 f2b(float f) {
  union { float f; unsigned u; } v; v.f = f;
  unsigned r = v.u + 0x7fffu + ((v.u >> 16) & 1u);
  return (u16)(r >> 16);
}
DEVI float b2f(u16 b) {
  union { unsigned u; float f; } v; v.u = ((unsigned)b) << 16;
  return v.f;
}

// async global->LDS, 16B per lane. LDS dest must be wave-uniform base + lane*16.
DEVI void gload_lds16(const void* gptr, void* lptr) {
  typedef const __attribute__((address_space(1))) unsigned gq;
  typedef __attribute__((address_space(3))) unsigned lq;
  __builtin_amdgcn_global_load_lds((gq*)(uintptr_t)gptr,
                                   (lq*)(uint32_t)(uintptr_t)lptr, 16, 0, 0);
}

// v_cvt_pk_bf16_f32: lo=bf16(a), hi=bf16(b)
DEVI unsigned cvtpk(float a, float b) {
  unsigned d;
  asm("v_cvt_pk_bf16_f32 %0, %1, %2" : "=v"(d) : "v"(a), "v"(b));
  return d;
}
// 16x16x16 bf16 MFMA (A,B = 4 bf16 each; k-map: lane (g,c15) holds k=g*4+j)
DEVI f32x4 mfma16(s16x4 a, s16x4 b, f32x4 c) {
  f32x4 d;
  asm("v_mfma_f32_16x16x16_bf16 %0, %1, %2, %3" : "=v"(d) : "v"(a), "v"(b), "v"(c));
  return d;
}

// ---------------------------------------------------------------------------
// f32 -> bf16 conversion (vectorized, grid-stride)
// ---------------------------------------------------------------------------
__global__ __launch_bounds__(256) void cvt_bf16(const float* __restrict__ src,
                                                u16* __restrict__ dst, int n4) {
  int i = blockIdx.x * 256 + threadIdx.x;
  const int stride = gridDim.x * 256;
  for (; i < n4; i += stride) {
    f32x4 v = *(const f32x4*)(src + (size_t)i * 4);
    u16x4 o;
    o[0] = f2b(v[0]); o[1] = f2b(v[1]); o[2] = f2b(v[2]); o[3] = f2b(v[3]);
    *(u16x4*)(dst + (size_t)i * 4) = o;
  }
}

// ---------------------------------------------------------------------------
// GEMM: C[M,N] = A[M,K](bf16) * B[N,K]^T(bf16). 128x128 tile, BK=64, 4 waves.
// OUT_BF16: write bf16 (f2b) instead of f32.
// ---------------------------------------------------------------------------
template <int OUT_BF16>
__global__ __launch_bounds__(256) void gemm_bt(const u16* __restrict__ A,
                                               const u16* __restrict__ B,
                                               void* __restrict__ Cv,
                                               int M, int N, int K) {
  __shared__ __align__(16) u16 As[128 * 64];
  __shared__ __align__(16) u16 Bs[128 * 64];
  const int tid = threadIdx.x;
  const int lane = tid & 63, w = tid >> 6;
  const int wm = w >> 1, wn = w & 1;
  const int c15 = lane & 15, g = lane >> 4;
  const int m0 = blockIdx.y * 128, n0 = blockIdx.x * 128;
  f32x4 acc[4][4] = {};

  for (int k0 = 0; k0 < K; k0 += 64) {
#pragma unroll
    for (int p = 0; p < 4; ++p) {
      const int c = tid + p * 256;
      const int row = c >> 3, ko = (c & 7) * 8;
      gload_lds16(A + (size_t)(m0 + row) * K + k0 + ko, &As[c * 8]);
    }
#pragma unroll
    for (int p = 0; p < 4; ++p) {
      const int c = tid + p * 256;
      const int row = c >> 3, ko = (c & 7) * 8;
      gload_lds16(B + (size_t)(n0 + row) * K + k0 + ko, &Bs[c * 8]);
    }
    __syncthreads();
#pragma unroll
    for (int kk = 0; kk < 64; kk += 32) {
      s16x8 af[4], bfr[4];
#pragma unroll
      for (int i = 0; i < 4; ++i)
        af[i] = *(const s16x8*)&As[(wm * 64 + i * 16 + c15) * 64 + kk + g * 8];
#pragma unroll
      for (int i = 0; i < 4; ++i)
        bfr[i] = *(const s16x8*)&Bs[(wn * 64 + i * 16 + c15) * 64 + kk + g * 8];
#pragma unroll
      for (int i = 0; i < 4; ++i)
#pragma unroll
        for (int j = 0; j < 4; ++j)
          acc[i][j] = __builtin_amdgcn_mfma_f32_16x16x32_bf16(af[i], bfr[j], acc[i][j], 0, 0, 0);
    }
    __syncthreads();
  }
#pragma unroll
  for (int i = 0; i < 4; ++i)
#pragma unroll
    for (int j = 0; j < 4; ++j) {
      const int mr = m0 + wm * 64 + i * 16 + g * 4;
      const int nc = n0 + wn * 64 + j * 16 + c15;
#pragma unroll
      for (int r = 0; r < 4; ++r) {
        if (OUT_BF16)
          ((u16*)Cv)[(size_t)(mr + r) * N + nc] = f2b(acc[i][j][r]);
        else
          ((float*)Cv)[(size_t)(mr + r) * N + nc] = acc[i][j][r];
      }
    }
}

// ---------------------------------------------------------------------------
// Per-row: RMSNorm(q_a[0:1024]) -> qn bf16 ; RMSNorm(ckv[0:896]) -> kvn bf16 ;
// RoPE(ckv[896:960]) -> kr bf16.  C1 row layout: [q_a(1024) | ckv(960) | pad]
// ---------------------------------------------------------------------------
DEVI float block_sum(float v, float* sbuf, int tid) {
#pragma unroll
  for (int o = 32; o; o >>= 1) v += __shfl_xor(v, o, 64);
  __syncthreads();
  if ((tid & 63) == 0) sbuf[tid >> 6] = v;
  __syncthreads();
  return sbuf[0] + sbuf[1] + sbuf[2] + sbuf[3];
}

__global__ __launch_bounds__(256) void norm_rope(const float* __restrict__ C1,
    const float* __restrict__ qw, const float* __restrict__ kw,
    const float* __restrict__ cosb, const float* __restrict__ sinb,
    u16* __restrict__ qn, u16* __restrict__ kvn, u16* __restrict__ kr) {
  __shared__ float sbuf[4];
  const int s = blockIdx.x, tid = threadIdx.x;
  const float* row = C1 + (size_t)s * 2048;

  f32x4 qv = *(const f32x4*)(row + tid * 4);
  float ss = qv[0]*qv[0] + qv[1]*qv[1] + qv[2]*qv[2] + qv[3]*qv[3];
  ss = block_sum(ss, sbuf, tid);
  const float scale = rsqrtf(ss * (1.f / 1024.f) + 1e-6f);
  {
    f32x4 wv = *(const f32x4*)(qw + tid * 4);
    u16x4 o;
#pragma unroll
    for (int j = 0; j < 4; ++j) o[j] = f2b(qv[j] * scale * wv[j]);
    *(u16x4*)(qn + (size_t)s * 1024 + tid * 4) = o;
  }

  float ss2 = 0.f;
  f32x4 kvv = {};
  if (tid < 224) {
    kvv = *(const f32x4*)(row + 1024 + tid * 4);
    ss2 = kvv[0]*kvv[0] + kvv[1]*kvv[1] + kvv[2]*kvv[2] + kvv[3]*kvv[3];
  }
  ss2 = block_sum(ss2, sbuf, tid);
  const float sc2 = rsqrtf(ss2 * (1.f / 896.f) + 1e-6f);
  if (tid < 224) {
    f32x4 wv = *(const f32x4*)(kw + tid * 4);
    u16x4 o;
#pragma unroll
    for (int j = 0; j < 4; ++j) o[j] = f2b(kvv[j] * sc2 * wv[j]);
    *(u16x4*)(kvn + (size_t)s * 896 + tid * 4) = o;
  }

  if (tid < 64) {
    const int d = tid;
    const float x = row[1920 + d];
    const float part = row[1920 + (d < 32 ? d + 32 : d - 32)];
    const float cv = cosb[s * 64 + d], sv = sinb[s * 64 + d];
    kr[(size_t)s * 64 + d] = f2b(d < 32 ? (x * cv - part * sv) : (x * cv + part * sv));
  }
}

// ---------------------------------------------------------------------------
// prep_kv: build swizzled Kb[h][s][128] (nope | roped kr) and Vt[h][d][s]
// from bf16 kvraw. Swizzle: within-row byte ^= ((row&7)<<4); inverse applied
// here so attn can global_load_lds linearly and XOR on ds_read.
// ---------------------------------------------------------------------------
__global__ __launch_bounds__(256) void prep_kv(const u16* __restrict__ kvb,
                                               const u16* __restrict__ kr,
                                               u16* __restrict__ Kb,
                                               u16* __restrict__ Vt) {
  __shared__ u16 t[64][80];
  const int tid = threadIdx.x, h = blockIdx.y, s0 = blockIdx.x * 64;
  {
    const int sl = tid >> 2, c2 = tid & 3;
    const size_t obyte = ((size_t)h * 2048 + s0 + sl) * 256;
    const int swz = (sl & 7) << 4;
#pragma unroll
    for (int gi = 0; gi < 4; ++gi) {
      const int b = c2 * 64 + gi * 16;  // byte within 256B row
      u16x8 v;
      if (c2 < 2)
        v = *(const u16x8*)(kvb + (size_t)(s0 + sl) * 4096 + h * 128 + c2 * 32 + gi * 8);
      else
        v = *(const u16x8*)(kr + (size_t)(s0 + sl) * 64 + (c2 - 2) * 32 + gi * 8);
      *(u16x8*)((char*)Kb + obyte + (b ^ swz)) = v;
    }
  }
  {
    const int r = tid >> 2, dc = tid & 3;
#pragma unroll
    for (int gi = 0; gi < 2; ++gi)
      *(u16x8*)&t[r][dc * 16 + gi * 8] =
          *(const u16x8*)(kvb + (size_t)(s0 + r) * 4096 + h * 128 + 64 + dc * 16 + gi * 8);
  }
  __syncthreads();
  {
    const int d = tid >> 2, sc = tid & 3;
    const size_t vbyte = ((size_t)h * 64 + d) * 4096 + 2 * (size_t)s0;
    const int swz = (d & 7) << 4;
#pragma unroll
    for (int k0 = 0; k0 < 16; k0 += 4) {
      u16x4 o;
#pragma unroll
      for (int k = 0; k < 4; ++k) o[k] = t[sc * 16 + k0 + k][d];
      *(u16x4*)((char*)Vt + vbyte + ((32 * sc + 2 * k0) ^ swz)) = o;
    }
  }
}

// ---------------------------------------------------------------------------
// Causal flash attention v2. Block=(pair of 64-row q-tiles, head), 4 waves.
// KVBLK=64. K/V staged via global_load_lds from pre-swizzled Kb/Vt.
// scores^T = mfma_x32(K, Q^T); O^T += mfma_x16(V^T, P^T) (no P shuffle).
// ---------------------------------------------------------------------------
__global__ __launch_bounds__(256) void attn_fwd(
    const u16* __restrict__ Qb, const u16* __restrict__ Kb,
    const u16* __restrict__ Vt, const float* __restrict__ cosb,
    const float* __restrict__ sinb, u16* __restrict__ attn) {
  __shared__ __align__(16) u16 Klds[64 * 128];  // swizzled [kv][128]
  __shared__ __align__(16) u16 Vlds[64 * 64];   // swizzled [d][kv]
  const int tid = threadIdx.x;
  const int lane = tid & 63, w = tid >> 6;
  const int c15 = lane & 15, g = lane >> 4;
  const int h = blockIdx.y;
  const u16* KbH = Kb + (size_t)h * 2048 * 128;
  const u16* VtH = Vt + (size_t)h * 64 * 2048;

  for (int half = 0; half < 2; ++half) {
    const int qb = half ? 31 - blockIdx.x : blockIdx.x;
    const int qrow = qb * 64 + w * 16 + c15;

    // Q fragments (B operand, k=d): qf[d0][i] = Q[qrow][d0*32+g*8+i], RoPE d>=64
    s16x8 qf[4];
    {
      const u16* qp = Qb + (size_t)qrow * 4096 + h * 128;
      qf[0] = __builtin_bit_cast(s16x8, *(const u16x8*)(qp + g * 8));
      qf[1] = __builtin_bit_cast(s16x8, *(const u16x8*)(qp + 32 + g * 8));
      u16x8 x2 = *(const u16x8*)(qp + 64 + g * 8);
      u16x8 x3 = *(const u16x8*)(qp + 96 + g * 8);
      const float* cb = cosb + (size_t)qrow * 64 + g * 8;
      const float* sb = sinb + (size_t)qrow * 64 + g * 8;
#pragma unroll
      for (int i = 0; i < 8; ++i) {
        const float f2 = b2f(x2[i]), f3 = b2f(x3[i]);
        qf[2][i] = (short)f2b(f2 * cb[i] - f3 * sb[i]);
        qf[3][i] = (short)f2b(f3 * cb[32 + i] + f2 * sb[32 + i]);
      }
    }

    f32x4 acc[4] = {};
    float m = -1e9f, ssum = 0.f;
    const int nt = qb + 1;

    for (int t = 0; t < nt; ++t) {
      const int kv0 = t * 64;
#pragma unroll
      for (int p = 0; p < 4; ++p) {
        const int c = tid + p * 256;
        gload_lds16(KbH + (size_t)(kv0 + (c >> 4)) * 128 + (c & 15) * 8,
                    (char*)Klds + c * 16);
      }
#pragma unroll
      for (int p = 0; p < 2; ++p) {
        const int c = tid + p * 256;
        gload_lds16(VtH + (size_t)(c >> 3) * 2048 + kv0 + (c & 7) * 8,
                    (char*)Vlds + c * 16);
      }
      __syncthreads();

      // scores^T for this wave's 16 q-cols
      float pv[4][4];
      float pm = -1e9f;
#pragma unroll
      for (int kvh = 0; kvh < 4; ++kvh) {
        f32x4 s4 = {};
        const int rb = (kvh * 16 + c15) * 256;
#pragma unroll
        for (int d0 = 0; d0 < 4; ++d0) {
          s16x8 kf = *(const s16x8*)((const char*)Klds + rb +
                                     ((d0 * 64 + g * 16) ^ ((c15 & 7) << 4)));
          s4 = __builtin_amdgcn_mfma_f32_16x16x32_bf16(kf, qf[d0], s4, 0, 0, 0);
        }
#pragma unroll
        for (int r = 0; r < 4; ++r) {
          const int kv = kv0 + kvh * 16 + g * 4 + r;
          float sc = s4[r] * 0.08838834764831845f;  // (HD+MD)^-0.5
          sc = (kv <= qrow) ? sc : -1e9f;
          pv[kvh][r] = sc;
          pm = fmaxf(pm, sc);
        }
      }
      pm = fmaxf(pm, __shfl_xor(pm, 16, 64));
      pm = fmaxf(pm, __shfl_xor(pm, 32, 64));
      const float mnew = fmaxf(m, pm);
      const float alpha = __expf(m - mnew);
      float rs = 0.f;
#pragma unroll
      for (int kvh = 0; kvh < 4; ++kvh)
#pragma unroll
        for (int r = 0; r < 4; ++r) {
          const float p = __expf(pv[kvh][r] - mnew);
          pv[kvh][r] = p;
          rs += p;
        }
      rs += __shfl_xor(rs, 16, 64);
      rs += __shfl_xor(rs, 32, 64);
      ssum = ssum * alpha + rs;
      m = mnew;
#pragma unroll
      for (int dt = 0; dt < 4; ++dt) acc[dt] *= alpha;

      // P^T -> bf16 B-frags (k=g*4+j matches score rows g*4+r: no shuffle)
      s16x4 pB[4];
#pragma unroll
      for (int ks = 0; ks < 4; ++ks) {
        u32x2 pw;
        pw[0] = cvtpk(pv[ks][0], pv[ks][1]);
        pw[1] = cvtpk(pv[ks][2], pv[ks][3]);
        pB[ks] = __builtin_bit_cast(s16x4, pw);
      }
#pragma unroll
      for (int dt = 0; dt < 4; ++dt) {
        const int rb2 = (dt * 16 + c15) * 128;
#pragma unroll
        for (int ks = 0; ks < 4; ++ks) {
          s16x4 vf = *(const s16x4*)((const char*)Vlds + rb2 +
                                     ((ks * 32 + g * 8) ^ ((c15 & 7) << 4)));
          acc[dt] = mfma16(vf, pB[ks], acc[dt]);
        }
      }
      __syncthreads();
    }

    const float inv = 1.f / ssum;
#pragma unroll
    for (int dt = 0; dt < 4; ++dt) {
      u16x4 o;
#pragma unroll
      for (int r = 0; r < 4; ++r) o[r] = f2b(acc[dt][r] * inv);
      *(u16x4*)(attn + (size_t)qrow * 2048 + h * 64 + dt * 16 + g * 4) = o;
    }
  }
}

// ---------------------------------------------------------------------------
extern "C" void kernel_launch(void* const* d_in, const int* in_sizes, int n_in,
                              void* d_out, int out_size, void* d_ws, size_t ws_size,
                              hipStream_t stream) {
  const float* X    = (const float*)d_in[0];
  const float* cosb = (const float*)d_in[1];
  const float* sinb = (const float*)d_in[2];
  const float* Wqa  = (const float*)d_in[3];
  const float* qlnw = (const float*)d_in[4];
  const float* Wqb  = (const float*)d_in[5];
  const float* Wkva = (const float*)d_in[6];
  const float* klnw = (const float*)d_in[7];
  const float* Wkvb = (const float*)d_in[8];
  const float* Wo   = (const float*)d_in[9];
  float* out = (float*)d_out;
  char* ws = (char*)d_ws;

  // workspace layout (bytes); total 90,963,968 (86.75 MiB)
  u16*   Xb     = (u16*)(ws + 0);          // [0,8M)    dies after GEMM1
  u16*   W1     = (u16*)(ws + 8388608);    // [8,16M)   dies after GEMM1
  float* C1     = (float*)(ws + 16777216); // [16,32M)  dies after norm
  u16*   qn     = (u16*)(ws + 33554432);   // [32,36M)
  u16*   kvn    = (u16*)(ws + 37748736);   // [36,39.5M)
  u16*   kr     = (u16*)(ws + 41418752);   // [39.5,39.75M)
  u16*   Wqbb   = (u16*)(ws + 41680896);   // [39.75,47.75M) Wob overlays
  u16*   Wkvbb  = (u16*)(ws + 50069504);   // [47.75,54.75M)
  u16*   qraw_b = (u16*)(ws + 0);          // [0,16M)  bf16, overlays Xb+W1
  u16*   kvraw_b= (u16*)(ws + 16777216);   // [16,32M) bf16, overlays C1
  u16*   Kb     = (u16*)(ws + 57409536);   // [54.75,70.75M)
  u16*   VtG    = (u16*)(ws + 74186752);   // [70.75,78.75M)
  u16*   attnb  = (u16*)(ws + 82575360);   // [78.75,86.75M)
  u16*   Wob    = Wqbb;

  auto cvt = [&](const float* s, u16* d, int n4) {
    int blocks = (n4 + 255) / 256; if (blocks > 1024) blocks = 1024;
    cvt_bf16<<<blocks, 256, 0, stream>>>(s, d, n4);
  };

  // 1. convert inputs/weights to bf16
  cvt(X,    Xb,                 2048 * 2048 / 4);
  cvt(Wqa,  W1,                 1024 * 2048 / 4);
  cvt(Wkva, W1 + 1024 * 2048,    960 * 2048 / 4);
  cvt(Wqb,  Wqbb,               4096 * 1024 / 4);
  cvt(Wkvb, Wkvbb,              4096 * 896 / 4);

  // 2. C1 = X @ [Wqa;Wkva]^T
  gemm_bt<0><<<dim3(16, 16), 256, 0, stream>>>(Xb, W1, C1, 2048, 2048, 2048);

  // 3. RMSNorm + k_rope RoPE
  norm_rope<<<2048, 256, 0, stream>>>(C1, qlnw, klnw, cosb, sinb, qn, kvn, kr);

  // 4. qraw_b = qn @ Wqb^T ; kvraw_b = kvn @ Wkvb^T  (bf16 outputs)
  gemm_bt<1><<<dim3(32, 16), 256, 0, stream>>>(qn, Wqbb, qraw_b, 2048, 4096, 1024);
  gemm_bt<1><<<dim3(32, 16), 256, 0, stream>>>(kvn, Wkvbb, kvraw_b, 2048, 4096, 896);

  // 5. Wo -> bf16 (overlays Wqbb; stream-ordered after GEMM2)
  cvt(Wo, Wob, 2048 * 2048 / 4);

  // 6. swizzled Kb + Vt
  prep_kv<<<dim3(32, 32), 256, 0, stream>>>(kvraw_b, kr, Kb, VtG);

  // 7. causal attention (paired q-tiles x and 31-x: constant work/block)
  attn_fwd<<<dim3(16, 32), 256, 0, stream>>>(qraw_b, Kb, VtG, cosb, sinb, attnb);

  // 8. out = attn @ Wo^T
  gemm_bt<0><<<dim3(16, 16), 256, 0, stream>>>(attnb, Wob, out, 2048, 2048, 2048);
}

// Round 3
// 253.177 us; speedup vs baseline: 1.5959x; 1.0672x over previous
//
#include <hip/hip_runtime.h>
#include <stdint.h>

typedef unsigned short u16;
typedef __attribute__((ext_vector_type(4))) float f32x4;
typedef __attribute__((ext_vector_type(4))) unsigned short u16x4;
typedef __attribute__((ext_vector_type(8))) unsigned short u16x8;
typedef __attribute__((ext_vector_type(8))) short s16x8;
typedef __attribute__((ext_vector_type(4))) short s16x4;
typedef __attribute__((ext_vector_type(2))) unsigned int u32x2;

#define DEVI static __device__ __forceinline__

// f32 -> bf16 round-to-nearest-even
DEVI u16 f2b(float f) {
  union { float f; unsigned u; } v; v.f = f;
  unsigned r = v.u + 0x7fffu + ((v.u >> 16) & 1u);
  return (u16)(r >> 16);
}
DEVI float b2f(u16 b) {
  union { unsigned u; float f; } v; v.u = ((unsigned)b) << 16;
  return v.f;
}

// async global->LDS, 16B per lane. LDS dest must be wave-uniform base + lane*16.
DEVI void gload_lds16(const void* gptr, void* lptr) {
  typedef const __attribute__((address_space(1))) unsigned gq;
  typedef __attribute__((address_space(3))) unsigned lq;
  __builtin_amdgcn_global_load_lds((gq*)(uintptr_t)gptr,
                                   (lq*)(uint32_t)(uintptr_t)lptr, 16, 0, 0);
}

// v_cvt_pk_bf16_f32: lo=bf16(a), hi=bf16(b)
DEVI unsigned cvtpk(float a, float b) {
  unsigned d;
  asm("v_cvt_pk_bf16_f32 %0, %1, %2" : "=v"(d) : "v"(a), "v"(b));
  return d;
}
// 16x16x16 bf16 MFMA (A,B = 4 bf16 each; k-map: lane (g,c15) holds k=g*4+j)
DEVI f32x4 mfma16(s16x4 a, s16x4 b, f32x4 c) {
  f32x4 d;
  asm("v_mfma_f32_16x16x16_bf16 %0, %1, %2, %3" : "=v"(d) : "v"(a), "v"(b), "v"(c));
  return d;
}
// v_exp_f32 is exp2
DEVI float exp2a(float x) {
  float d;
  asm("v_exp_f32 %0, %1" : "=v"(d) : "v"(x));
  return d;
}

// ---------------------------------------------------------------------------
// f32 -> bf16 conversion (vectorized, grid-stride)
// ---------------------------------------------------------------------------
__global__ __launch_bounds__(256) void cvt_bf16(const float* __restrict__ src,
                                                u16* __restrict__ dst, int n4) {
  int i = blockIdx.x * 256 + threadIdx.x;
  const int stride = gridDim.x * 256;
  for (; i < n4; i += stride) {
    f32x4 v = *(const f32x4*)(src + (size_t)i * 4);
    u16x4 o;
    o[0] = f2b(v[0]); o[1] = f2b(v[1]); o[2] = f2b(v[2]); o[3] = f2b(v[3]);
    *(u16x4*)(dst + (size_t)i * 4) = o;
  }
}

// ---------------------------------------------------------------------------
// GEMM: C[M,N] = A[M,K](bf16) * B[N,K]^T(bf16). 128x128 tile, BK=64, 4 waves.
// OUT_BF16: write bf16 instead of f32.
// ---------------------------------------------------------------------------
template <int OUT_BF16>
__global__ __launch_bounds__(256) void gemm_bt(const u16* __restrict__ A,
                                               const u16* __restrict__ B,
                                               void* __restrict__ Cv,
                                               int M, int N, int K) {
  __shared__ __align__(16) u16 As[128 * 64];
  __shared__ __align__(16) u16 Bs[128 * 64];
  const int tid = threadIdx.x;
  const int lane = tid & 63, w = tid >> 6;
  const int wm = w >> 1, wn = w & 1;
  const int c15 = lane & 15, g = lane >> 4;
  const int m0 = blockIdx.y * 128, n0 = blockIdx.x * 128;
  f32x4 acc[4][4] = {};

  for (int k0 = 0; k0 < K; k0 += 64) {
#pragma unroll
    for (int p = 0; p < 4; ++p) {
      const int c = tid + p * 256;
      gload_lds16(A + (size_t)(m0 + (c >> 3)) * K + k0 + (c & 7) * 8, &As[c * 8]);
    }
#pragma unroll
    for (int p = 0; p < 4; ++p) {
      const int c = tid + p * 256;
      gload_lds16(B + (size_t)(n0 + (c >> 3)) * K + k0 + (c & 7) * 8, &Bs[c * 8]);
    }
    __syncthreads();
#pragma unroll
    for (int kk = 0; kk < 64; kk += 32) {
      s16x8 af[4], bfr[4];
#pragma unroll
      for (int i = 0; i < 4; ++i)
        af[i] = *(const s16x8*)&As[(wm * 64 + i * 16 + c15) * 64 + kk + g * 8];
#pragma unroll
      for (int i = 0; i < 4; ++i)
        bfr[i] = *(const s16x8*)&Bs[(wn * 64 + i * 16 + c15) * 64 + kk + g * 8];
#pragma unroll
      for (int i = 0; i < 4; ++i)
#pragma unroll
        for (int j = 0; j < 4; ++j)
          acc[i][j] = __builtin_amdgcn_mfma_f32_16x16x32_bf16(af[i], bfr[j], acc[i][j], 0, 0, 0);
    }
    __syncthreads();
  }
#pragma unroll
  for (int i = 0; i < 4; ++i)
#pragma unroll
    for (int j = 0; j < 4; ++j) {
      const int mr = m0 + wm * 64 + i * 16 + g * 4;
      const int nc = n0 + wn * 64 + j * 16 + c15;
#pragma unroll
      for (int r = 0; r < 4; ++r) {
        if (OUT_BF16)
          ((u16*)Cv)[(size_t)(mr + r) * N + nc] = f2b(acc[i][j][r]);
        else
          ((float*)Cv)[(size_t)(mr + r) * N + nc] = acc[i][j][r];
      }
    }
}

// ---------------------------------------------------------------------------
// GEMM2b: kv = kvn @ Wkvb^T, epilogue scatters directly into swizzled
// Kb[h][s][0:64] (k_nope) and Vt[h][d][s] (value).  N=4096 (32 heads x 128).
// ---------------------------------------------------------------------------
__global__ __launch_bounds__(256) void gemm_kv(const u16* __restrict__ A,
                                               const u16* __restrict__ B,
                                               char* __restrict__ KbB,
                                               char* __restrict__ VtB,
                                               int M, int K) {
  __shared__ __align__(16) u16 As[128 * 64];
  __shared__ __align__(16) u16 Bs[128 * 64];
  const int tid = threadIdx.x;
  const int lane = tid & 63, w = tid >> 6;
  const int wm = w >> 1, wn = w & 1;
  const int c15 = lane & 15, g = lane >> 4;
  const int m0 = blockIdx.y * 128, n0 = blockIdx.x * 128;
  const int N = 4096;
  f32x4 acc[4][4] = {};

  for (int k0 = 0; k0 < K; k0 += 64) {
#pragma unroll
    for (int p = 0; p < 4; ++p) {
      const int c = tid + p * 256;
      gload_lds16(A + (size_t)(m0 + (c >> 3)) * K + k0 + (c & 7) * 8, &As[c * 8]);
    }
#pragma unroll
    for (int p = 0; p < 4; ++p) {
      const int c = tid + p * 256;
      gload_lds16(B + (size_t)(n0 + (c >> 3)) * K + k0 + (c & 7) * 8, &Bs[c * 8]);
    }
    __syncthreads();
#pragma unroll
    for (int kk = 0; kk < 64; kk += 32) {
      s16x8 af[4], bfr[4];
#pragma unroll
      for (int i = 0; i < 4; ++i)
        af[i] = *(const s16x8*)&As[(wm * 64 + i * 16 + c15) * 64 + kk + g * 8];
#pragma unroll
      for (int i = 0; i < 4; ++i)
        bfr[i] = *(const s16x8*)&Bs[(wn * 64 + i * 16 + c15) * 64 + kk + g * 8];
#pragma unroll
      for (int i = 0; i < 4; ++i)
#pragma unroll
        for (int j = 0; j < 4; ++j)
          acc[i][j] = __builtin_amdgcn_mfma_f32_16x16x32_bf16(af[i], bfr[j], acc[i][j], 0, 0, 0);
    }
    __syncthreads();
  }
  const int h = n0 >> 7;  // 128-col tile == one head
#pragma unroll
  for (int i = 0; i < 4; ++i)
#pragma unroll
    for (int j = 0; j < 4; ++j) {
      const int mr = m0 + wm * 64 + i * 16 + g * 4;  // s0 (mult of 4)
      if (wn == 0) {
        const int d = j * 16 + c15;                  // k_nope col
#pragma unroll
        for (int r = 0; r < 4; ++r) {
          const int s = mr + r;
          *(u16*)(KbB + ((size_t)(h * 2048 + s) << 8) +
                  ((2 * d) ^ ((s & 7) << 4))) = f2b(acc[i][j][r]);
        }
      } else {
        const int d = j * 16 + c15;                  // value col (0..63)
        u16x4 o;
#pragma unroll
        for (int r = 0; r < 4; ++r) o[r] = f2b(acc[i][j][r]);
        *(u16x4*)(VtB + ((size_t)(h * 64 + d) << 12) +
                  ((2 * mr) ^ ((d & 7) << 4))) = o;
      }
    }
}

// ---------------------------------------------------------------------------
// Per-row: RMSNorm(q_a)->qn, RMSNorm(ckv)->kvn, RoPE(k_rope)-> broadcast into
// Kb[h][s][64:128] (swizzled) for all 32 heads.
// ---------------------------------------------------------------------------
DEVI float block_sum(float v, float* sbuf, int tid) {
#pragma unroll
  for (int o = 32; o; o >>= 1) v += __shfl_xor(v, o, 64);
  __syncthreads();
  if ((tid & 63) == 0) sbuf[tid >> 6] = v;
  __syncthreads();
  return sbuf[0] + sbuf[1] + sbuf[2] + sbuf[3];
}

__global__ __launch_bounds__(256) void norm_rope(const float* __restrict__ C1,
    const float* __restrict__ qw, const float* __restrict__ kw,
    const float* __restrict__ cosb, const float* __restrict__ sinb,
    u16* __restrict__ qn, u16* __restrict__ kvn, char* __restrict__ KbB) {
  __shared__ float sbuf[4];
  __shared__ __align__(16) u16 rv[64];
  const int s = blockIdx.x, tid = threadIdx.x;
  const float* row = C1 + (size_t)s * 2048;

  f32x4 qv = *(const f32x4*)(row + tid * 4);
  float ss = qv[0]*qv[0] + qv[1]*qv[1] + qv[2]*qv[2] + qv[3]*qv[3];
  ss = block_sum(ss, sbuf, tid);
  const float scale = rsqrtf(ss * (1.f / 1024.f) + 1e-6f);
  {
    f32x4 wv = *(const f32x4*)(qw + tid * 4);
    u16x4 o;
#pragma unroll
    for (int j = 0; j < 4; ++j) o[j] = f2b(qv[j] * scale * wv[j]);
    *(u16x4*)(qn + (size_t)s * 1024 + tid * 4) = o;
  }

  float ss2 = 0.f;
  f32x4 kvv = {};
  if (tid < 224) {
    kvv = *(const f32x4*)(row + 1024 + tid * 4);
    ss2 = kvv[0]*kvv[0] + kvv[1]*kvv[1] + kvv[2]*kvv[2] + kvv[3]*kvv[3];
  }
  ss2 = block_sum(ss2, sbuf, tid);
  const float sc2 = rsqrtf(ss2 * (1.f / 896.f) + 1e-6f);
  if (tid < 224) {
    f32x4 wv = *(const f32x4*)(kw + tid * 4);
    u16x4 o;
#pragma unroll
    for (int j = 0; j < 4; ++j) o[j] = f2b(kvv[j] * sc2 * wv[j]);
    *(u16x4*)(kvn + (size_t)s * 896 + tid * 4) = o;
  }

  if (tid < 64) {
    const int d = tid;
    const float x = row[1920 + d];
    const float part = row[1920 + (d < 32 ? d + 32 : d - 32)];
    const float cv = cosb[s * 64 + d], sv = sinb[s * 64 + d];
    rv[d] = f2b(d < 32 ? (x * cv - part * sv) : (x * cv + part * sv));
  }
  __syncthreads();
  // broadcast roped-k into all 32 heads' Kb rows (16B vector, swizzled)
  {
    const int h = tid >> 3, c8 = tid & 7;
    const u16x8 v = *(const u16x8*)&rv[c8 * 8];
    *(u16x8*)(KbB + ((size_t)(h * 2048 + s) << 8) +
              ((128 + c8 * 16) ^ ((s & 7) << 4))) = v;
  }
}

// ---------------------------------------------------------------------------
// Causal flash attention v3. 1024 blocks (one 64-row q-tile x head), 4 waves.
// XCD-chunked remap (4 heads/XCD) + LPT (big qb first). Double-buffered K/V
// with prefetch-before-compute (T3 2-phase). Softmax in exp2 domain.
// ---------------------------------------------------------------------------
__global__ __launch_bounds__(256) void attn_fwd(
    const u16* __restrict__ Qb, const u16* __restrict__ Kb,
    const u16* __restrict__ Vt, const float* __restrict__ cosb,
    const float* __restrict__ sinb, u16* __restrict__ attn) {
  __shared__ __align__(16) u16 Klds[2][64 * 128];  // swizzled [kv][128]
  __shared__ __align__(16) u16 Vlds[2][64 * 64];   // swizzled [d][kv]
  const int tid = threadIdx.x;
  const int lane = tid & 63, w = tid >> 6;
  const int c15 = lane & 15, g = lane >> 4;
  // XCD-chunked bijective remap: xcd = orig%8 owns 128 logical blocks
  const int orig = blockIdx.x;
  const int l = (orig & 7) * 128 + (orig >> 3);
  const int h = l >> 5;
  const int qb = 31 - (l & 31);  // LPT: large qb dispatched first
  const int qrow = qb * 64 + w * 16 + c15;
  const char* KbHB = (const char*)Kb + ((size_t)h << 19);          // h*2048*256
  const char* VtHB = (const char*)Vt + ((size_t)h << 18);          // h*64*4096
  const float SC2 = 0.12753860478587782f;  // (HD+MD)^-0.5 * log2(e)

  // Q fragments (B operand, k=d), scaled by SC2, RoPE on d>=64
  s16x8 qf[4];
  {
    const u16* qp = Qb + (size_t)qrow * 4096 + h * 128;
    u16x8 x0 = *(const u16x8*)(qp + g * 8);
    u16x8 x1 = *(const u16x8*)(qp + 32 + g * 8);
    u16x8 x2 = *(const u16x8*)(qp + 64 + g * 8);
    u16x8 x3 = *(const u16x8*)(qp + 96 + g * 8);
    const float* cb = cosb + (size_t)qrow * 64 + g * 8;
    const float* sb = sinb + (size_t)qrow * 64 + g * 8;
#pragma unroll
    for (int i = 0; i < 8; ++i) {
      qf[0][i] = (short)f2b(b2f(x0[i]) * SC2);
      qf[1][i] = (short)f2b(b2f(x1[i]) * SC2);
      const float f2 = b2f(x2[i]), f3 = b2f(x3[i]);
      qf[2][i] = (short)f2b((f2 * cb[i] - f3 * sb[i]) * SC2);
      qf[3][i] = (short)f2b((f3 * cb[32 + i] + f2 * sb[32 + i]) * SC2);
    }
  }

  const int nt = qb + 1;
  auto STAGE = [&](int t, int buf) {
    const int kv0 = t << 6;
#pragma unroll
    for (int p = 0; p < 4; ++p) {
      const int c = tid + p * 256;
      gload_lds16(KbHB + ((size_t)(kv0 + (c >> 4)) << 8) + (c & 15) * 16,
                  (char*)Klds[buf] + c * 16);
    }
#pragma unroll
    for (int p = 0; p < 2; ++p) {
      const int c = tid + p * 256;
      gload_lds16(VtHB + ((size_t)(c >> 3) << 12) + 2 * kv0 + (c & 7) * 16,
                  (char*)Vlds[buf] + c * 16);
    }
  };

  f32x4 acc[4] = {};
  float m = -1e9f, ssum = 0.f;

  STAGE(0, 0);
  __syncthreads();

  for (int t = 0; t < nt; ++t) {
    const int cur = t & 1;
    const int kv0 = t << 6;
    if (t + 1 < nt) STAGE(t + 1, cur ^ 1);  // prefetch overlaps compute

    const u16* Kc = Klds[cur];
    const u16* Vc = Vlds[cur];

    // scores^T (already x SC2 via Q)
    float pv[4][4];
    float pm = -1e9f;
    __builtin_amdgcn_s_setprio(1);
#pragma unroll
    for (int kvh = 0; kvh < 4; ++kvh) {
      f32x4 s4 = {};
      const int rb = (kvh * 16 + c15) * 256;
#pragma unroll
      for (int d0 = 0; d0 < 4; ++d0) {
        s16x8 kf = *(const s16x8*)((const char*)Kc + rb +
                                   ((d0 * 64 + g * 16) ^ ((c15 & 7) << 4)));
        s4 = __builtin_amdgcn_mfma_f32_16x16x32_bf16(kf, qf[d0], s4, 0, 0, 0);
      }
      pv[kvh][0] = s4[0]; pv[kvh][1] = s4[1];
      pv[kvh][2] = s4[2]; pv[kvh][3] = s4[3];
    }
    __builtin_amdgcn_s_setprio(0);
    if (t == nt - 1) {  // only diagonal tile needs the causal mask
#pragma unroll
      for (int kvh = 0; kvh < 4; ++kvh)
#pragma unroll
        for (int r = 0; r < 4; ++r) {
          const int kv = kv0 + kvh * 16 + g * 4 + r;
          if (kv > qrow) pv[kvh][r] = -1e9f;
        }
    }
#pragma unroll
    for (int kvh = 0; kvh < 4; ++kvh)
#pragma unroll
      for (int r = 0; r < 4; ++r) pm = fmaxf(pm, pv[kvh][r]);
    pm = fmaxf(pm, __shfl_xor(pm, 16, 64));
    pm = fmaxf(pm, __shfl_xor(pm, 32, 64));
    const float mnew = fmaxf(m, pm);
    const float alpha = exp2a(m - mnew);
    float rs = 0.f;
#pragma unroll
    for (int kvh = 0; kvh < 4; ++kvh)
#pragma unroll
      for (int r = 0; r < 4; ++r) {
        const float p = exp2a(pv[kvh][r] - mnew);
        pv[kvh][r] = p;
        rs += p;
      }
    rs += __shfl_xor(rs, 16, 64);
    rs += __shfl_xor(rs, 32, 64);
    ssum = ssum * alpha + rs;
    m = mnew;
#pragma unroll
    for (int dt = 0; dt < 4; ++dt) acc[dt] *= alpha;

    // P^T -> bf16 B-frags (k=g*4+j matches score rows: no shuffle)
    s16x4 pB[4];
#pragma unroll
    for (int ks = 0; ks < 4; ++ks) {
      u32x2 pw;
      pw[0] = cvtpk(pv[ks][0], pv[ks][1]);
      pw[1] = cvtpk(pv[ks][2], pv[ks][3]);
      pB[ks] = __builtin_bit_cast(s16x4, pw);
    }
    __builtin_amdgcn_s_setprio(1);
#pragma unroll
    for (int dt = 0; dt < 4; ++dt) {
      const int rb2 = (dt * 16 + c15) * 128;
#pragma unroll
      for (int ks = 0; ks < 4; ++ks) {
        s16x4 vf = *(const s16x4*)((const char*)Vc + rb2 +
                                   ((ks * 32 + g * 8) ^ ((c15 & 7) << 4)));
        acc[dt] = mfma16(vf, pB[ks], acc[dt]);
      }
    }
    __builtin_amdgcn_s_setprio(0);
    __syncthreads();  // drains vmcnt(0): prefetched buf ready, cur reusable
  }

  const float inv = 1.f / ssum;
#pragma unroll
  for (int dt = 0; dt < 4; ++dt) {
    u16x4 o;
#pragma unroll
    for (int r = 0; r < 4; ++r) o[r] = f2b(acc[dt][r] * inv);
    *(u16x4*)(attn + (size_t)qrow * 2048 + h * 64 + dt * 16 + g * 4) = o;
  }
}

// ---------------------------------------------------------------------------
extern "C" void kernel_launch(void* const* d_in, const int* in_sizes, int n_in,
                              void* d_out, int out_size, void* d_ws, size_t ws_size,
                              hipStream_t stream) {
  const float* X    = (const float*)d_in[0];
  const float* cosb = (const float*)d_in[1];
  const float* sinb = (const float*)d_in[2];
  const float* Wqa  = (const float*)d_in[3];
  const float* qlnw = (const float*)d_in[4];
  const float* Wqb  = (const float*)d_in[5];
  const float* Wkva = (const float*)d_in[6];
  const float* klnw = (const float*)d_in[7];
  const float* Wkvb = (const float*)d_in[8];
  const float* Wo   = (const float*)d_in[9];
  float* out = (float*)d_out;
  char* ws = (char*)d_ws;

  // workspace layout (bytes); total 86.75 MiB
  u16*   Xb     = (u16*)(ws + 0);          // [0,8M)    dies after GEMM1
  u16*   W1     = (u16*)(ws + 8388608);    // [8,16M)   dies after GEMM1
  float* C1     = (float*)(ws + 16777216); // [16,32M)  dies after norm
  u16*   qn     = (u16*)(ws + 33554432);   // [32,36M)
  u16*   kvn    = (u16*)(ws + 37748736);   // [36,39.5M)
  u16*   Wqbb   = (u16*)(ws + 41680896);   // [39.75,47.75M) Wob overlays
  u16*   Wkvbb  = (u16*)(ws + 50069504);   // [47.75,54.75M)
  u16*   qraw_b = (u16*)(ws + 0);          // [0,16M)  bf16, overlays Xb+W1
  u16*   Kb     = (u16*)(ws + 57409536);   // [54.75,70.75M) 32h x 2048 x 256B
  u16*   VtG    = (u16*)(ws + 74186752);   // [70.75,78.75M) 32h x 64 x 4096B
  u16*   attnb  = (u16*)(ws + 82575360);   // [78.75,86.75M)
  u16*   Wob    = Wqbb;

  auto cvt = [&](const float* s, u16* d, int n4) {
    int blocks = (n4 + 255) / 256; if (blocks > 1024) blocks = 1024;
    cvt_bf16<<<blocks, 256, 0, stream>>>(s, d, n4);
  };

  // 1. convert inputs/weights to bf16
  cvt(X,    Xb,                 2048 * 2048 / 4);
  cvt(Wqa,  W1,                 1024 * 2048 / 4);
  cvt(Wkva, W1 + 1024 * 2048,    960 * 2048 / 4);
  cvt(Wqb,  Wqbb,               4096 * 1024 / 4);
  cvt(Wkvb, Wkvbb,              4096 * 896 / 4);

  // 2. C1 = X @ [Wqa;Wkva]^T
  gemm_bt<0><<<dim3(16, 16), 256, 0, stream>>>(Xb, W1, C1, 2048, 2048, 2048);

  // 3. RMSNorm + roped-k broadcast into Kb[..][64:128]
  norm_rope<<<2048, 256, 0, stream>>>(C1, qlnw, klnw, cosb, sinb, qn, kvn, (char*)Kb);

  // 4. qraw_b = qn @ Wqb^T ; {Kb,Vt} <- kvn @ Wkvb^T (fused epilogue)
  gemm_bt<1><<<dim3(32, 16), 256, 0, stream>>>(qn, Wqbb, qraw_b, 2048, 4096, 1024);
  gemm_kv<<<dim3(32, 16), 256, 0, stream>>>(kvn, Wkvbb, (char*)Kb, (char*)VtG, 2048, 896);

  // 5. Wo -> bf16 (overlays Wqbb; stream-ordered after GEMM2a)
  cvt(Wo, Wob, 2048 * 2048 / 4);

  // 6. causal attention
  attn_fwd<<<1024, 256, 0, stream>>>(qraw_b, Kb, VtG, cosb, sinb, attnb);

  // 7. out = attn @ Wo^T
  gemm_bt<0><<<dim3(16, 16), 256, 0, stream>>>(attnb, Wob, out, 2048, 2048, 2048);
}

// Round 4
// 206.643 us; speedup vs baseline: 1.9553x; 1.2252x over previous
//
#include <hip/hip_runtime.h>
#include <stdint.h>

typedef unsigned short u16;
typedef __attribute__((ext_vector_type(4))) float f32x4;
typedef __attribute__((ext_vector_type(4))) unsigned short u16x4;
typedef __attribute__((ext_vector_type(8))) unsigned short u16x8;
typedef __attribute__((ext_vector_type(8))) short s16x8;
typedef __attribute__((ext_vector_type(4))) short s16x4;
typedef __attribute__((ext_vector_type(2))) unsigned int u32x2;

#define DEVI static __device__ __forceinline__

// f32 -> bf16 round-to-nearest-even
DEVI u16 f2b(float f) {
  union { float f; unsigned u; } v; v.f = f;
  unsigned r = v.u + 0x7fffu + ((v.u >> 16) & 1u);
  return (u16)(r >> 16);
}
DEVI float b2f(u16 b) {
  union { unsigned u; float f; } v; v.u = ((unsigned)b) << 16;
  return v.f;
}

// async global->LDS, 16B per lane. LDS dest must be wave-uniform base + lane*16.
DEVI void gload_lds16(const void* gptr, void* lptr) {
  typedef const __attribute__((address_space(1))) unsigned gq;
  typedef __attribute__((address_space(3))) unsigned lq;
  __builtin_amdgcn_global_load_lds((gq*)(uintptr_t)gptr,
                                   (lq*)(uint32_t)(uintptr_t)lptr, 16, 0, 0);
}

// v_cvt_pk_bf16_f32: lo=bf16(a), hi=bf16(b)
DEVI unsigned cvtpk(float a, float b) {
  unsigned d;
  asm("v_cvt_pk_bf16_f32 %0, %1, %2" : "=v"(d) : "v"(a), "v"(b));
  return d;
}
// 16x16x16 bf16 MFMA (A,B = 4 bf16 each; k-map: lane (g,c15) holds k=g*4+j)
DEVI f32x4 mfma16(s16x4 a, s16x4 b, f32x4 c) {
  f32x4 d;
  asm("v_mfma_f32_16x16x16_bf16 %0, %1, %2, %3" : "=v"(d) : "v"(a), "v"(b), "v"(c));
  return d;
}
// v_exp_f32 is exp2
DEVI float exp2a(float x) {
  float d;
  asm("v_exp_f32 %0, %1" : "=v"(d) : "v"(x));
  return d;
}

// ---------------------------------------------------------------------------
// All f32 -> bf16 conversions in one dispatch (6 segments, hardcoded bounds).
// ---------------------------------------------------------------------------
__global__ __launch_bounds__(256) void cvt_all(
    const float* __restrict__ X, const float* __restrict__ Wqa,
    const float* __restrict__ Wkva, const float* __restrict__ Wqb,
    const float* __restrict__ Wkvb, const float* __restrict__ Wo,
    u16* __restrict__ Xb, u16* __restrict__ W1, u16* __restrict__ Wqbb,
    u16* __restrict__ Wkvbb, u16* __restrict__ Wob) {
  int i = blockIdx.x * 256 + threadIdx.x;
  const int stride = gridDim.x * 256;
  for (; i < 5079040; i += stride) {   // units of f32x4
    const float* s; u16* d; int j;
    if (i < 1572864) {
      if (i < 1048576) { s = X; d = Xb; j = i; }
      else             { s = Wqa; d = W1; j = i - 1048576; }
    } else if (i < 3112960) {
      if (i < 2064384) { s = Wkva; d = W1 + 1024 * 2048; j = i - 1572864; }
      else             { s = Wqb; d = Wqbb; j = i - 2064384; }
    } else {
      if (i < 4030464) { s = Wkvb; d = Wkvbb; j = i - 3112960; }
      else             { s = Wo; d = Wob; j = i - 4030464; }
    }
    f32x4 v = *(const f32x4*)(s + (size_t)j * 4);
    u16x4 o;
    o[0] = f2b(v[0]); o[1] = f2b(v[1]); o[2] = f2b(v[2]); o[3] = f2b(v[3]);
    *(u16x4*)(d + (size_t)j * 4) = o;
  }
}

// ---------------------------------------------------------------------------
// GEMM core macros: 128x128 tile, BK=64, 4 waves, double-buffered LDS with
// prefetch-before-compute (T3 2-phase), ONE barrier per K-step.
// ---------------------------------------------------------------------------
#define GEMM_STAGE(AP, BP, KK, k0, buf)                                        \
  {                                                                            \
    _Pragma("unroll") for (int p = 0; p < 4; ++p) {                            \
      const int c = tid + p * 256;                                             \
      gload_lds16(AP + (size_t)(m0 + (c >> 3)) * (KK) + (k0) + (c & 7) * 8,    \
                  &As[buf][c * 8]);                                            \
    }                                                                          \
    _Pragma("unroll") for (int p = 0; p < 4; ++p) {                            \
      const int c = tid + p * 256;                                             \
      gload_lds16(BP + (size_t)(n0 + (c >> 3)) * (KK) + (k0) + (c & 7) * 8,    \
                  &Bs[buf][c * 8]);                                            \
    }                                                                          \
  }

#define GEMM_COMPUTE(cur)                                                      \
  _Pragma("unroll") for (int kk = 0; kk < 64; kk += 32) {                      \
    s16x8 af[4], bfr[4];                                                       \
    _Pragma("unroll") for (int i = 0; i < 4; ++i)                              \
      af[i] = *(const s16x8*)&As[cur][(wm * 64 + i * 16 + c15) * 64 + kk + g * 8]; \
    _Pragma("unroll") for (int i = 0; i < 4; ++i)                              \
      bfr[i] = *(const s16x8*)&Bs[cur][(wn * 64 + i * 16 + c15) * 64 + kk + g * 8]; \
    _Pragma("unroll") for (int i = 0; i < 4; ++i)                              \
      _Pragma("unroll") for (int j = 0; j < 4; ++j)                            \
        acc[i][j] = __builtin_amdgcn_mfma_f32_16x16x32_bf16(af[i], bfr[j],     \
                                                            acc[i][j], 0, 0, 0); \
  }

// GEMM with f32 output (GEMM1, GEMM3)
__global__ __launch_bounds__(256) void gemm_f32(const u16* __restrict__ A,
                                                const u16* __restrict__ B,
                                                float* __restrict__ C,
                                                int M, int N, int K) {
  __shared__ __align__(16) u16 As[2][128 * 64];
  __shared__ __align__(16) u16 Bs[2][128 * 64];
  const int tid = threadIdx.x;
  const int lane = tid & 63, w = tid >> 6;
  const int wm = w >> 1, wn = w & 1;
  const int c15 = lane & 15, g = lane >> 4;
  const int m0 = blockIdx.y * 128, n0 = blockIdx.x * 128;
  f32x4 acc[4][4] = {};

  GEMM_STAGE(A, B, K, 0, 0);
  __syncthreads();
  const int nk = K >> 6;
  for (int kt = 0; kt < nk; ++kt) {
    const int cur = kt & 1;
    if (kt + 1 < nk) GEMM_STAGE(A, B, K, (kt + 1) << 6, cur ^ 1);
    GEMM_COMPUTE(cur);
    __syncthreads();
  }
#pragma unroll
  for (int i = 0; i < 4; ++i)
#pragma unroll
    for (int j = 0; j < 4; ++j) {
      const int mr = m0 + wm * 64 + i * 16 + g * 4;
      const int nc = n0 + wn * 64 + j * 16 + c15;
#pragma unroll
      for (int r = 0; r < 4; ++r)
        C[(size_t)(mr + r) * N + nc] = acc[i][j][r];
    }
}

// ---------------------------------------------------------------------------
// Fused GEMM2: z=0 -> qraw = qn @ Wqb^T (bf16, N=4096);
//              z=1 -> kv = kvn @ Wkvb^T, scatter into swizzled Kb/Vt.
// ---------------------------------------------------------------------------
__global__ __launch_bounds__(256) void gemm2_fused(
    const u16* __restrict__ qn, const u16* __restrict__ Wqbb,
    const u16* __restrict__ kvn, const u16* __restrict__ Wkvbb,
    u16* __restrict__ qraw, char* __restrict__ KbB, char* __restrict__ VtB) {
  __shared__ __align__(16) u16 As[2][128 * 64];
  __shared__ __align__(16) u16 Bs[2][128 * 64];
  const int z = blockIdx.z;
  const u16* A = z ? kvn : qn;
  const u16* B = z ? Wkvbb : Wqbb;
  const int K = z ? 896 : 1024;
  const int tid = threadIdx.x;
  const int lane = tid & 63, w = tid >> 6;
  const int wm = w >> 1, wn = w & 1;
  const int c15 = lane & 15, g = lane >> 4;
  const int m0 = blockIdx.y * 128, n0 = blockIdx.x * 128;
  f32x4 acc[4][4] = {};

  GEMM_STAGE(A, B, K, 0, 0);
  __syncthreads();
  const int nk = K >> 6;
  for (int kt = 0; kt < nk; ++kt) {
    const int cur = kt & 1;
    if (kt + 1 < nk) GEMM_STAGE(A, B, K, (kt + 1) << 6, cur ^ 1);
    GEMM_COMPUTE(cur);
    __syncthreads();
  }

  if (z == 0) {
#pragma unroll
    for (int i = 0; i < 4; ++i)
#pragma unroll
      for (int j = 0; j < 4; ++j) {
        const int mr = m0 + wm * 64 + i * 16 + g * 4;
        const int nc = n0 + wn * 64 + j * 16 + c15;
#pragma unroll
        for (int r = 0; r < 4; ++r)
          qraw[(size_t)(mr + r) * 4096 + nc] = f2b(acc[i][j][r]);
      }
  } else {
    const int h = n0 >> 7;  // 128-col tile == one head
#pragma unroll
    for (int i = 0; i < 4; ++i)
#pragma unroll
      for (int j = 0; j < 4; ++j) {
        const int mr = m0 + wm * 64 + i * 16 + g * 4;  // s0 (mult of 4)
        if (wn == 0) {
          const int d = j * 16 + c15;                  // k_nope col
#pragma unroll
          for (int r = 0; r < 4; ++r) {
            const int s = mr + r;
            *(u16*)(KbB + ((size_t)(h * 2048 + s) << 8) +
                    ((2 * d) ^ ((s & 7) << 4))) = f2b(acc[i][j][r]);
          }
        } else {
          const int d = j * 16 + c15;                  // value col (0..63)
          u16x4 o;
#pragma unroll
          for (int r = 0; r < 4; ++r) o[r] = f2b(acc[i][j][r]);
          *(u16x4*)(VtB + ((size_t)(h * 64 + d) << 12) +
                    ((2 * mr) ^ ((d & 7) << 4))) = o;
        }
      }
  }
}

// ---------------------------------------------------------------------------
// Per-row: RMSNorm(q_a)->qn, RMSNorm(ckv)->kvn, RoPE(k_rope)-> broadcast into
// Kb[h][s][64:128] (swizzled) for all 32 heads.
// ---------------------------------------------------------------------------
DEVI float block_sum(float v, float* sbuf, int tid) {
#pragma unroll
  for (int o = 32; o; o >>= 1) v += __shfl_xor(v, o, 64);
  __syncthreads();
  if ((tid & 63) == 0) sbuf[tid >> 6] = v;
  __syncthreads();
  return sbuf[0] + sbuf[1] + sbuf[2] + sbuf[3];
}

__global__ __launch_bounds__(256) void norm_rope(const float* __restrict__ C1,
    const float* __restrict__ qw, const float* __restrict__ kw,
    const float* __restrict__ cosb, const float* __restrict__ sinb,
    u16* __restrict__ qn, u16* __restrict__ kvn, char* __restrict__ KbB) {
  __shared__ float sbuf[4];
  __shared__ __align__(16) u16 rv[64];
  const int s = blockIdx.x, tid = threadIdx.x;
  const float* row = C1 + (size_t)s * 2048;

  f32x4 qv = *(const f32x4*)(row + tid * 4);
  float ss = qv[0]*qv[0] + qv[1]*qv[1] + qv[2]*qv[2] + qv[3]*qv[3];
  ss = block_sum(ss, sbuf, tid);
  const float scale = rsqrtf(ss * (1.f / 1024.f) + 1e-6f);
  {
    f32x4 wv = *(const f32x4*)(qw + tid * 4);
    u16x4 o;
#pragma unroll
    for (int j = 0; j < 4; ++j) o[j] = f2b(qv[j] * scale * wv[j]);
    *(u16x4*)(qn + (size_t)s * 1024 + tid * 4) = o;
  }

  float ss2 = 0.f;
  f32x4 kvv = {};
  if (tid < 224) {
    kvv = *(const f32x4*)(row + 1024 + tid * 4);
    ss2 = kvv[0]*kvv[0] + kvv[1]*kvv[1] + kvv[2]*kvv[2] + kvv[3]*kvv[3];
  }
  ss2 = block_sum(ss2, sbuf, tid);
  const float sc2 = rsqrtf(ss2 * (1.f / 896.f) + 1e-6f);
  if (tid < 224) {
    f32x4 wv = *(const f32x4*)(kw + tid * 4);
    u16x4 o;
#pragma unroll
    for (int j = 0; j < 4; ++j) o[j] = f2b(kvv[j] * sc2 * wv[j]);
    *(u16x4*)(kvn + (size_t)s * 896 + tid * 4) = o;
  }

  if (tid < 64) {
    const int d = tid;
    const float x = row[1920 + d];
    const float part = row[1920 + (d < 32 ? d + 32 : d - 32)];
    const float cv = cosb[s * 64 + d], sv = sinb[s * 64 + d];
    rv[d] = f2b(d < 32 ? (x * cv - part * sv) : (x * cv + part * sv));
  }
  __syncthreads();
  {
    const int h = tid >> 3, c8 = tid & 7;
    const u16x8 v = *(const u16x8*)&rv[c8 * 8];
    *(u16x8*)(KbB + ((size_t)(h * 2048 + s) << 8) +
              ((128 + c8 * 16) ^ ((s & 7) << 4))) = v;
  }
}

// ---------------------------------------------------------------------------
// Causal flash attention v3 + defer-max (T13). 1024 blocks, 4 waves.
// ---------------------------------------------------------------------------
__global__ __launch_bounds__(256) void attn_fwd(
    const u16* __restrict__ Qb, const u16* __restrict__ Kb,
    const u16* __restrict__ Vt, const float* __restrict__ cosb,
    const float* __restrict__ sinb, u16* __restrict__ attn) {
  __shared__ __align__(16) u16 Klds[2][64 * 128];  // swizzled [kv][128]
  __shared__ __align__(16) u16 Vlds[2][64 * 64];   // swizzled [d][kv]
  const int tid = threadIdx.x;
  const int lane = tid & 63, w = tid >> 6;
  const int c15 = lane & 15, g = lane >> 4;
  const int orig = blockIdx.x;
  const int l = (orig & 7) * 128 + (orig >> 3);
  const int h = l >> 5;
  const int qb = 31 - (l & 31);  // LPT: large qb dispatched first
  const int qrow = qb * 64 + w * 16 + c15;
  const char* KbHB = (const char*)Kb + ((size_t)h << 19);
  const char* VtHB = (const char*)Vt + ((size_t)h << 18);
  const float SC2 = 0.12753860478587782f;  // (HD+MD)^-0.5 * log2(e)

  s16x8 qf[4];
  {
    const u16* qp = Qb + (size_t)qrow * 4096 + h * 128;
    u16x8 x0 = *(const u16x8*)(qp + g * 8);
    u16x8 x1 = *(const u16x8*)(qp + 32 + g * 8);
    u16x8 x2 = *(const u16x8*)(qp + 64 + g * 8);
    u16x8 x3 = *(const u16x8*)(qp + 96 + g * 8);
    const float* cb = cosb + (size_t)qrow * 64 + g * 8;
    const float* sb = sinb + (size_t)qrow * 64 + g * 8;
#pragma unroll
    for (int i = 0; i < 8; ++i) {
      qf[0][i] = (short)f2b(b2f(x0[i]) * SC2);
      qf[1][i] = (short)f2b(b2f(x1[i]) * SC2);
      const float f2 = b2f(x2[i]), f3 = b2f(x3[i]);
      qf[2][i] = (short)f2b((f2 * cb[i] - f3 * sb[i]) * SC2);
      qf[3][i] = (short)f2b((f3 * cb[32 + i] + f2 * sb[32 + i]) * SC2);
    }
  }

  const int nt = qb + 1;
  auto STAGE = [&](int t, int buf) {
    const int kv0 = t << 6;
#pragma unroll
    for (int p = 0; p < 4; ++p) {
      const int c = tid + p * 256;
      gload_lds16(KbHB + ((size_t)(kv0 + (c >> 4)) << 8) + (c & 15) * 16,
                  (char*)Klds[buf] + c * 16);
    }
#pragma unroll
    for (int p = 0; p < 2; ++p) {
      const int c = tid + p * 256;
      gload_lds16(VtHB + ((size_t)(c >> 3) << 12) + 2 * kv0 + (c & 7) * 16,
                  (char*)Vlds[buf] + c * 16);
    }
  };

  f32x4 acc[4] = {};
  float m = -1e9f, ssum = 0.f;

  STAGE(0, 0);
  __syncthreads();

  for (int t = 0; t < nt; ++t) {
    const int cur = t & 1;
    const int kv0 = t << 6;
    if (t + 1 < nt) STAGE(t + 1, cur ^ 1);

    const u16* Kc = Klds[cur];
    const u16* Vc = Vlds[cur];

    float pv[4][4];
    float pm = -1e9f;
    __builtin_amdgcn_s_setprio(1);
#pragma unroll
    for (int kvh = 0; kvh < 4; ++kvh) {
      f32x4 s4 = {};
      const int rb = (kvh * 16 + c15) * 256;
#pragma unroll
      for (int d0 = 0; d0 < 4; ++d0) {
        s16x8 kf = *(const s16x8*)((const char*)Kc + rb +
                                   ((d0 * 64 + g * 16) ^ ((c15 & 7) << 4)));
        s4 = __builtin_amdgcn_mfma_f32_16x16x32_bf16(kf, qf[d0], s4, 0, 0, 0);
      }
      pv[kvh][0] = s4[0]; pv[kvh][1] = s4[1];
      pv[kvh][2] = s4[2]; pv[kvh][3] = s4[3];
    }
    __builtin_amdgcn_s_setprio(0);
    if (t == nt - 1) {
#pragma unroll
      for (int kvh = 0; kvh < 4; ++kvh)
#pragma unroll
        for (int r = 0; r < 4; ++r) {
          const int kv = kv0 + kvh * 16 + g * 4 + r;
          if (kv > qrow) pv[kvh][r] = -1e9f;
        }
    }
#pragma unroll
    for (int kvh = 0; kvh < 4; ++kvh)
#pragma unroll
      for (int r = 0; r < 4; ++r) pm = fmaxf(pm, pv[kvh][r]);
    pm = fmaxf(pm, __shfl_xor(pm, 16, 64));
    pm = fmaxf(pm, __shfl_xor(pm, 32, 64));
    // defer-max (T13): only rescale when tile max exceeds m by > 8 (exp2 dom.)
    if (!__all(pm - m <= 8.f)) {
      const float mnew = fmaxf(m, pm);
      const float alpha = exp2a(m - mnew);
      ssum *= alpha;
#pragma unroll
      for (int dt = 0; dt < 4; ++dt) acc[dt] *= alpha;
      m = mnew;
    }
    float rs = 0.f;
#pragma unroll
    for (int kvh = 0; kvh < 4; ++kvh)
#pragma unroll
      for (int r = 0; r < 4; ++r) {
        const float p = exp2a(pv[kvh][r] - m);
        pv[kvh][r] = p;
        rs += p;
      }
    rs += __shfl_xor(rs, 16, 64);
    rs += __shfl_xor(rs, 32, 64);
    ssum += rs;

    s16x4 pB[4];
#pragma unroll
    for (int ks = 0; ks < 4; ++ks) {
      u32x2 pw;
      pw[0] = cvtpk(pv[ks][0], pv[ks][1]);
      pw[1] = cvtpk(pv[ks][2], pv[ks][3]);
      pB[ks] = __builtin_bit_cast(s16x4, pw);
    }
    __builtin_amdgcn_s_setprio(1);
#pragma unroll
    for (int dt = 0; dt < 4; ++dt) {
      const int rb2 = (dt * 16 + c15) * 128;
#pragma unroll
      for (int ks = 0; ks < 4; ++ks) {
        s16x4 vf = *(const s16x4*)((const char*)Vc + rb2 +
                                   ((ks * 32 + g * 8) ^ ((c15 & 7) << 4)));
        acc[dt] = mfma16(vf, pB[ks], acc[dt]);
      }
    }
    __builtin_amdgcn_s_setprio(0);
    __syncthreads();
  }

  const float inv = 1.f / ssum;
#pragma unroll
  for (int dt = 0; dt < 4; ++dt) {
    u16x4 o;
#pragma unroll
    for (int r = 0; r < 4; ++r) o[r] = f2b(acc[dt][r] * inv);
    *(u16x4*)(attn + (size_t)qrow * 2048 + h * 64 + dt * 16 + g * 4) = o;
  }
}

// ---------------------------------------------------------------------------
extern "C" void kernel_launch(void* const* d_in, const int* in_sizes, int n_in,
                              void* d_out, int out_size, void* d_ws, size_t ws_size,
                              hipStream_t stream) {
  const float* X    = (const float*)d_in[0];
  const float* cosb = (const float*)d_in[1];
  const float* sinb = (const float*)d_in[2];
  const float* Wqa  = (const float*)d_in[3];
  const float* qlnw = (const float*)d_in[4];
  const float* Wqb  = (const float*)d_in[5];
  const float* Wkva = (const float*)d_in[6];
  const float* klnw = (const float*)d_in[7];
  const float* Wkvb = (const float*)d_in[8];
  const float* Wo   = (const float*)d_in[9];
  float* out = (float*)d_out;
  char* ws = (char*)d_ws;

  // workspace layout (bytes); total 96 MiB
  u16*   Xb     = (u16*)(ws + 0);          // [0,8M)     dies after GEMM1
  u16*   W1     = (u16*)(ws + 8388608);    // [8,16M)    dies after GEMM1
  float* C1     = (float*)(ws + 16777216); // [16,32M)   dies after norm
  u16*   qn     = (u16*)(ws + 33554432);   // [32,36M)
  u16*   kvn    = (u16*)(ws + 37748736);   // [36,39.5M)
  u16*   Wqbb   = (u16*)(ws + 41943040);   // [40,48M)
  u16*   Wkvbb  = (u16*)(ws + 50331648);   // [48,55M)
  u16*   qraw_b = (u16*)(ws + 0);          // [0,16M)  overlays Xb+W1
  u16*   Kb     = (u16*)(ws + 58720256);   // [56,72M)  32h x 2048 x 256B
  u16*   VtG    = (u16*)(ws + 75497472);   // [72,80M)  32h x 64 x 4096B
  u16*   attnb  = (u16*)(ws + 83886080);   // [80,88M)
  u16*   Wob    = (u16*)(ws + 92274688);   // [88,96M)

  // 1. all f32->bf16 conversions in one dispatch
  cvt_all<<<2048, 256, 0, stream>>>(X, Wqa, Wkva, Wqb, Wkvb, Wo,
                                    Xb, W1, Wqbb, Wkvbb, Wob);

  // 2. C1 = X @ [Wqa;Wkva]^T
  gemm_f32<<<dim3(16, 16), 256, 0, stream>>>(Xb, W1, C1, 2048, 2048, 2048);

  // 3. RMSNorm + roped-k broadcast into Kb[..][64:128]
  norm_rope<<<2048, 256, 0, stream>>>(C1, qlnw, klnw, cosb, sinb, qn, kvn, (char*)Kb);

  // 4. fused: qraw_b = qn @ Wqb^T  and  {Kb,Vt} <- kvn @ Wkvb^T
  gemm2_fused<<<dim3(32, 16, 2), 256, 0, stream>>>(qn, Wqbb, kvn, Wkvbb,
                                                   qraw_b, (char*)Kb, (char*)VtG);

  // 5. causal attention
  attn_fwd<<<1024, 256, 0, stream>>>(qraw_b, Kb, VtG, cosb, sinb, attnb);

  // 6. out = attn @ Wo^T
  gemm_f32<<<dim3(16, 16), 256, 0, stream>>>(attnb, Wob, out, 2048, 2048, 2048);
}